// Round 1
// baseline (832.387 us; speedup 1.0000x reference)
//
#include <hip/hip_runtime.h>
#include <cstdint>
#include <cstddef>

#define NN 100000
#define NE 1600000
#define DD 64
#define NG 64

constexpr int SCAN_B = 1024;
constexpr int SCAN_NB = (NN + SCAN_B - 1) / SCAN_B; // 98

__global__ void k_count(const int* __restrict__ dst, int* __restrict__ counts) {
    int i = blockIdx.x * blockDim.x + threadIdx.x;
    int stride = gridDim.x * blockDim.x;
    for (; i < NE; i += stride)
        atomicAdd(&counts[dst[i]], 1);
}

__global__ void k_scan1(const int* __restrict__ counts, int* __restrict__ excl,
                        float* __restrict__ deg_inv, int* __restrict__ bsum) {
    __shared__ int s[2][SCAN_B];
    int t = threadIdx.x;
    int i = blockIdx.x * SCAN_B + t;
    int v = (i < NN) ? counts[i] : 0;
    s[0][t] = v;
    __syncthreads();
    int src = 0;
    for (int off = 1; off < SCAN_B; off <<= 1) {
        int x = s[src][t];
        if (t >= off) x += s[src][t - off];
        s[src ^ 1][t] = x;
        __syncthreads();
        src ^= 1;
    }
    int incl = s[src][t];
    if (i < NN) {
        excl[i] = incl - v;                       // block-local exclusive scan
        deg_inv[i] = (v > 0) ? 1.0f / (float)v : 0.0f;
    }
    if (t == SCAN_B - 1) bsum[blockIdx.x] = incl; // block total
}

__global__ void k_scan2(int* __restrict__ bsum) {
    __shared__ int s[2][128];
    int t = threadIdx.x;
    int v = (t < SCAN_NB) ? bsum[t] : 0;
    s[0][t] = v;
    __syncthreads();
    int src = 0;
    for (int off = 1; off < 128; off <<= 1) {
        int x = s[src][t];
        if (t >= off) x += s[src][t - off];
        s[src ^ 1][t] = x;
        __syncthreads();
        src ^= 1;
    }
    if (t < SCAN_NB) bsum[t] = s[src][t] - v;     // exclusive over block totals
}

__global__ void k_scan3(int* __restrict__ row_off, int* __restrict__ cursor,
                        const int* __restrict__ bsum) {
    int i = blockIdx.x * blockDim.x + threadIdx.x;
    if (i < NN) {
        int r = row_off[i] + bsum[i / SCAN_B];
        row_off[i] = r;
        cursor[i] = r;
    }
    if (i == 0) row_off[NN] = NE;
}

__global__ void k_scatter(const int* __restrict__ src, const int* __restrict__ dst,
                          int* __restrict__ cursor, int* __restrict__ srcs) {
    int i = blockIdx.x * blockDim.x + threadIdx.x;
    int stride = gridDim.x * blockDim.x;
    for (; i < NE; i += stride) {
        int pos = atomicAdd(&cursor[dst[i]], 1);
        srcs[pos] = src[i];
    }
}

// Fused: agg = (segment_sum h[src]) * deg_inv ; out = agg@Wl^T + bl + h@Wr^T ; relu?
// One wave per node; lane = feature dim. Wl/Wr rows live in registers (lane j
// holds row j). acc/x rows cross-lane via per-wave LDS broadcast.
__global__ void __launch_bounds__(256) k_layer(
    const float* __restrict__ hin, float* __restrict__ hout,
    const float* __restrict__ Wl, const float* __restrict__ bl,
    const float* __restrict__ Wr,
    const int* __restrict__ row_off, const int* __restrict__ srcs,
    const float* __restrict__ deg_inv, int relu) {
    __shared__ __align__(16) int   ids[4][64];
    __shared__ __align__(16) float stg[4][2][64];
    const int lane = threadIdx.x & 63;
    const int wid  = threadIdx.x >> 6;
    const int gw   = blockIdx.x * 4 + wid;
    const int total_waves = gridDim.x * 4;

    // lane j holds Wl[j][0..63] and Wr[j][0..63]
    float wl[DD], wr[DD];
#pragma unroll
    for (int kq = 0; kq < DD / 4; ++kq) {
        float4 a = *(const float4*)&Wl[lane * DD + kq * 4];
        wl[kq*4+0] = a.x; wl[kq*4+1] = a.y; wl[kq*4+2] = a.z; wl[kq*4+3] = a.w;
        float4 b = *(const float4*)&Wr[lane * DD + kq * 4];
        wr[kq*4+0] = b.x; wr[kq*4+1] = b.y; wr[kq*4+2] = b.z; wr[kq*4+3] = b.w;
    }
    const float bias = bl[lane];

    for (int n = gw; n < NN; n += total_waves) {
        const int beg = row_off[n];
        const int end = row_off[n + 1];
        float acc = 0.f;
        for (int base = beg; base < end; base += 64) {
            int m = end - base; if (m > 64) m = 64;
            if (lane < m) ids[wid][lane] = srcs[base + lane];
            __builtin_amdgcn_wave_barrier();
            int jq = 0;
            for (; jq + 4 <= m; jq += 4) {
                int4 s4 = *(const int4*)&ids[wid][jq];   // wave-broadcast
                float v0 = hin[(size_t)s4.x * DD + lane];
                float v1 = hin[(size_t)s4.y * DD + lane];
                float v2 = hin[(size_t)s4.z * DD + lane];
                float v3 = hin[(size_t)s4.w * DD + lane];
                acc += (v0 + v1) + (v2 + v3);
            }
            for (; jq < m; ++jq)
                acc += hin[(size_t)ids[wid][jq] * DD + lane];
            __builtin_amdgcn_wave_barrier();
        }
        acc *= deg_inv[n];
        const float xv = hin[(size_t)n * DD + lane];
        stg[wid][0][lane] = acc;
        stg[wid][1][lane] = xv;
        __builtin_amdgcn_wave_barrier();
        float out = bias;
        const float4* sa = (const float4*)&stg[wid][0][0];
        const float4* sx = (const float4*)&stg[wid][1][0];
#pragma unroll
        for (int kq = 0; kq < DD / 4; ++kq) {
            float4 a4 = sa[kq];                          // wave-broadcast
            float4 x4 = sx[kq];
            out += a4.x * wl[kq*4+0] + a4.y * wl[kq*4+1]
                 + a4.z * wl[kq*4+2] + a4.w * wl[kq*4+3];
            out += x4.x * wr[kq*4+0] + x4.y * wr[kq*4+1]
                 + x4.z * wr[kq*4+2] + x4.w * wr[kq*4+3];
        }
        if (relu) out = fmaxf(out, 0.f);
        hout[(size_t)n * DD + lane] = out;
        __builtin_amdgcn_wave_barrier();                 // protect stg reuse
    }
}

// Graph readout: batch is sorted; wave per 64-node chunk, register-accumulate
// runs of equal graph id, flush via atomicAdd per boundary.
__global__ void k_reduce(const float* __restrict__ h, const int* __restrict__ batch,
                         float* __restrict__ out) {
    const int lane = threadIdx.x & 63;
    const int wid  = threadIdx.x >> 6;
    const int gw   = blockIdx.x * 4 + wid;
    const int start = gw * 64;
    if (start >= NN) return;
    const int endn = (start + 64 < NN) ? start + 64 : NN;
    float acc = 0.f;
    int gcur = batch[start];
    for (int i = start; i < endn; ++i) {
        int g = batch[i];
        if (g != gcur) {
            atomicAdd(&out[gcur * DD + lane], acc);
            acc = 0.f;
            gcur = g;
        }
        acc += h[(size_t)i * DD + lane];
    }
    atomicAdd(&out[gcur * DD + lane], acc);
}

extern "C" void kernel_launch(void* const* d_in, const int* in_sizes, int n_in,
                              void* d_out, int out_size, void* d_ws, size_t ws_size,
                              hipStream_t stream) {
    const float* x     = (const float*)d_in[0];
    const int*   ei    = (const int*)d_in[1];
    const int*   batch = (const int*)d_in[2];
    const float* Wl[3] = {(const float*)d_in[3], (const float*)d_in[6], (const float*)d_in[9]};
    const float* bl[3] = {(const float*)d_in[4], (const float*)d_in[7], (const float*)d_in[10]};
    const float* Wr[3] = {(const float*)d_in[5], (const float*)d_in[8], (const float*)d_in[11]};
    float* out = (float*)d_out;

    char* ws = (char*)d_ws;
    size_t off = 0;
    auto alloc = [&](size_t bytes) -> void* {
        void* p = ws + off;
        off = (off + bytes + 255) & ~(size_t)255;
        return p;
    };
    int*   counts  = (int*)  alloc((size_t)NN * 4);
    float* deg_inv = (float*)alloc((size_t)NN * 4);
    int*   row_off = (int*)  alloc(((size_t)NN + 1) * 4);
    int*   cursor  = (int*)  alloc((size_t)NN * 4);
    int*   bsum    = (int*)  alloc(128 * 4);
    int*   srcs    = (int*)  alloc((size_t)NE * 4);
    float* hA      = (float*)alloc((size_t)NN * DD * 4);
    float* hB      = (float*)alloc((size_t)NN * DD * 4);

    const int* e_src = ei;       // edge_index[0]
    const int* e_dst = ei + NE;  // edge_index[1]

    hipMemsetAsync(counts, 0, (size_t)NN * 4, stream);
    hipMemsetAsync(out, 0, (size_t)NG * DD * 4, stream);

    k_count<<<2048, 256, 0, stream>>>(e_dst, counts);
    k_scan1<<<SCAN_NB, SCAN_B, 0, stream>>>(counts, row_off, deg_inv, bsum);
    k_scan2<<<1, 128, 0, stream>>>(bsum);
    k_scan3<<<(NN + 255) / 256, 256, 0, stream>>>(row_off, cursor, bsum);
    k_scatter<<<2048, 256, 0, stream>>>(e_src, e_dst, cursor, srcs);

    k_layer<<<1024, 256, 0, stream>>>(x,  hA, Wl[0], bl[0], Wr[0], row_off, srcs, deg_inv, 1);
    k_layer<<<1024, 256, 0, stream>>>(hA, hB, Wl[1], bl[1], Wr[1], row_off, srcs, deg_inv, 1);
    k_layer<<<1024, 256, 0, stream>>>(hB, hA, Wl[2], bl[2], Wr[2], row_off, srcs, deg_inv, 0);

    k_reduce<<<(NN / 64 + 4) / 4, 256, 0, stream>>>(hA, batch, out);
}

// Round 2
// 400.602 us; speedup vs baseline: 2.0778x; 2.0778x over previous
//
#include <hip/hip_runtime.h>
#include <cstdint>
#include <cstddef>

#define NN 100000
#define NE 1600000
#define DD 64
#define NG 64

typedef unsigned short u16;
typedef unsigned int u32;
typedef short short8 __attribute__((ext_vector_type(8)));
typedef float f32x4 __attribute__((ext_vector_type(4)));

constexpr int SCAN_B = 1024;
constexpr int SCAN_NB = (NN + SCAN_B - 1) / SCAN_B; // 98

__device__ __forceinline__ float bf2f(u16 h) {
    u32 u = ((u32)h) << 16;
    return __builtin_bit_cast(float, u);
}
__device__ __forceinline__ u16 f2bf(float f) {
    u32 u = __builtin_bit_cast(u32, f);
    u += 0x7fffu + ((u >> 16) & 1u);
    return (u16)(u >> 16);
}

// ---------------- CSR build ----------------
__global__ void k_count(const int* __restrict__ dst, int* __restrict__ counts) {
    int i = blockIdx.x * blockDim.x + threadIdx.x;
    int stride = gridDim.x * blockDim.x;
    for (; i < NE; i += stride)
        atomicAdd(&counts[dst[i]], 1);
}

__global__ void k_scan1(const int* __restrict__ counts, int* __restrict__ excl,
                        float* __restrict__ deg_inv, int* __restrict__ bsum) {
    __shared__ int s[2][SCAN_B];
    int t = threadIdx.x;
    int i = blockIdx.x * SCAN_B + t;
    int v = (i < NN) ? counts[i] : 0;
    s[0][t] = v;
    __syncthreads();
    int src = 0;
    for (int off = 1; off < SCAN_B; off <<= 1) {
        int x = s[src][t];
        if (t >= off) x += s[src][t - off];
        s[src ^ 1][t] = x;
        __syncthreads();
        src ^= 1;
    }
    int incl = s[src][t];
    if (i < NN) {
        excl[i] = incl - v;
        deg_inv[i] = (v > 0) ? 1.0f / (float)v : 0.0f;
    }
    if (t == SCAN_B - 1) bsum[blockIdx.x] = incl;
}

__global__ void k_scan2(int* __restrict__ bsum) {
    __shared__ int s[2][128];
    int t = threadIdx.x;
    int v = (t < SCAN_NB) ? bsum[t] : 0;
    s[0][t] = v;
    __syncthreads();
    int src = 0;
    for (int off = 1; off < 128; off <<= 1) {
        int x = s[src][t];
        if (t >= off) x += s[src][t - off];
        s[src ^ 1][t] = x;
        __syncthreads();
        src ^= 1;
    }
    if (t < SCAN_NB) bsum[t] = s[src][t] - v;
}

__global__ void k_scan3(int* __restrict__ row_off, int* __restrict__ cursor,
                        const int* __restrict__ bsum) {
    int i = blockIdx.x * blockDim.x + threadIdx.x;
    if (i < NN) {
        int r = row_off[i] + bsum[i / SCAN_B];
        row_off[i] = r;
        cursor[i] = r;
    }
    if (i == 0) row_off[NN] = NE;
}

__global__ void k_scatter(const int* __restrict__ src, const int* __restrict__ dst,
                          int* __restrict__ cursor, int* __restrict__ srcs) {
    int i = blockIdx.x * blockDim.x + threadIdx.x;
    int stride = gridDim.x * blockDim.x;
    for (; i < NE; i += stride) {
        int pos = atomicAdd(&cursor[dst[i]], 1);
        srcs[pos] = src[i];
    }
}

// ---------------- fp32 -> bf16 ----------------
__global__ void k_cvt(const float* __restrict__ x, u16* __restrict__ xb) {
    int i = blockIdx.x * blockDim.x + threadIdx.x;
    int stride = gridDim.x * blockDim.x;
    const int total = NN * DD / 4;
    for (; i < total; i += stride) {
        float4 v = ((const float4*)x)[i];
        u32 p0 = (u32)f2bf(v.x) | ((u32)f2bf(v.y) << 16);
        u32 p1 = (u32)f2bf(v.z) | ((u32)f2bf(v.w) << 16);
        uint2 pk; pk.x = p0; pk.y = p1;
        ((uint2*)xb)[i] = pk;
    }
}

// ---------------- gather: agg[n] = mean of h[src] rows (bf16 in/out) -------
// One wave per node. Rows are 128B; each load instr covers TWO neighbor rows:
// lanes 0-31 -> row ids[j], lanes 32-63 -> row ids[j+1], ushort2 per lane.
__global__ void __launch_bounds__(256) k_gather(
    const u16* __restrict__ hin, u16* __restrict__ agg,
    const int* __restrict__ row_off, const int* __restrict__ srcs,
    const float* __restrict__ deg_inv) {
    __shared__ int ids[4][64];
    const int lane = threadIdx.x & 63;
    const int wid  = threadIdx.x >> 6;
    const int half = lane >> 5;
    const int fp   = (lane & 31) * 2;   // feature pair base
    const int nw   = gridDim.x * 4;
    int n = blockIdx.x * 4 + wid;
    if (n >= NN) return;
    int beg = row_off[n], end = row_off[n + 1];
    int myid = (beg + lane < end) ? srcs[beg + lane] : 0;

#define PAIR(J, SLO, SHI) { \
        int _id = ids[wid][(J) + half]; \
        u32 _v = *(const u32*)&hin[(size_t)_id * DD + fp]; \
        SLO += __builtin_bit_cast(float, _v << 16); \
        SHI += __builtin_bit_cast(float, _v & 0xffff0000u); }

    while (true) {
        ids[wid][lane] = myid;
        __builtin_amdgcn_wave_barrier();
        // prefetch next node's ids into register (overlaps gathers below)
        int nn2 = n + nw;
        int beg2 = 0, end2 = 0;
        if (nn2 < NN) { beg2 = row_off[nn2]; end2 = row_off[nn2 + 1]; }
        myid = (nn2 < NN && beg2 + lane < end2) ? srcs[beg2 + lane] : 0;
        const float dinv = deg_inv[n];

        int deg = end - beg;
        int cnt = deg < 64 ? deg : 64;
        float s0 = 0.f, s1 = 0.f, t0 = 0.f, t1 = 0.f;
        float u0 = 0.f, u1 = 0.f, w0 = 0.f, w1 = 0.f;
        int jq = 0;
        for (; jq + 16 <= cnt; jq += 16) {   // 8 paired loads = 16 rows in flight
            PAIR(jq + 0,  s0, s1)
            PAIR(jq + 2,  t0, t1)
            PAIR(jq + 4,  u0, u1)
            PAIR(jq + 6,  w0, w1)
            PAIR(jq + 8,  s0, s1)
            PAIR(jq + 10, t0, t1)
            PAIR(jq + 12, u0, u1)
            PAIR(jq + 14, w0, w1)
        }
        for (; jq + 2 <= cnt; jq += 2) PAIR(jq, s0, s1)
        if (jq < cnt) {                      // odd leftover: lower half only
            int _id = ids[wid][jq];
            if (half == 0) {
                u32 _v = *(const u32*)&hin[(size_t)_id * DD + fp];
                s0 += __builtin_bit_cast(float, _v << 16);
                s1 += __builtin_bit_cast(float, _v & 0xffff0000u);
            }
        }
        // rare fallback: deg > 64
        for (int base = 64; base < deg; base += 64) {
            __builtin_amdgcn_wave_barrier();
            int m = deg - base; if (m > 64) m = 64;
            if (lane < m) ids[wid][lane] = srcs[beg + base + lane];
            __builtin_amdgcn_wave_barrier();
            int j = 0;
            for (; j + 2 <= m; j += 2) PAIR(j, s0, s1)
            if (j < m) {
                int _id = ids[wid][j];
                if (half == 0) {
                    u32 _v = *(const u32*)&hin[(size_t)_id * DD + fp];
                    s0 += __builtin_bit_cast(float, _v << 16);
                    s1 += __builtin_bit_cast(float, _v & 0xffff0000u);
                }
            }
        }
        float aLo = (s0 + t0) + (u0 + w0);
        float aHi = (s1 + t1) + (u1 + w1);
        aLo += __shfl_xor(aLo, 32);
        aHi += __shfl_xor(aHi, 32);
        aLo *= dinv; aHi *= dinv;
        if (half == 0) {
            u32 pk = (u32)f2bf(aLo) | ((u32)f2bf(aHi) << 16);
            *(u32*)&agg[(size_t)n * DD + fp] = pk;
        }
        n = nn2;
        if (n >= NN) break;
        beg = beg2; end = end2;
        __builtin_amdgcn_wave_barrier();
    }
#undef PAIR
}

// ---------------- linear: hout = agg@Wl^T + bl + h@Wr^T (+relu), bf16 MFMA -
// Wave owns 16-node tiles. Weights held as 16 B-fragments in registers.
__global__ void __launch_bounds__(256) k_linear(
    const u16* __restrict__ aggb, const u16* __restrict__ hb,
    u16* __restrict__ houtb,
    const float* __restrict__ Wl, const float* __restrict__ bl,
    const float* __restrict__ Wr, int relu) {
    const int lane = threadIdx.x & 63;
    const int wid  = threadIdx.x >> 6;
    const int r = lane & 15, g = lane >> 4;
    const int nw = gridDim.x * 4;
    const int w0 = blockIdx.x * 4 + wid;

    // b-frag: B[k][col] = W[col][k]; lane holds col=r, k = kc*32 + g*8 + e
    short8 bw[2][4][2];
#pragma unroll
    for (int m = 0; m < 2; ++m) {
        const float* W = m ? Wr : Wl;
#pragma unroll
        for (int ct = 0; ct < 4; ++ct)
#pragma unroll
            for (int kc = 0; kc < 2; ++kc) {
                const float* p = W + (size_t)(ct * 16 + r) * DD + kc * 32 + g * 8;
                float4 q0 = *(const float4*)p;
                float4 q1 = *(const float4*)(p + 4);
                short8 t;
                t[0] = (short)f2bf(q0.x); t[1] = (short)f2bf(q0.y);
                t[2] = (short)f2bf(q0.z); t[3] = (short)f2bf(q0.w);
                t[4] = (short)f2bf(q1.x); t[5] = (short)f2bf(q1.y);
                t[6] = (short)f2bf(q1.z); t[7] = (short)f2bf(q1.w);
                bw[m][ct][kc] = t;
            }
    }
    float bias[4];
#pragma unroll
    for (int ct = 0; ct < 4; ++ct) bias[ct] = bl[ct * 16 + r];

    for (int t = w0; t < NN / 16; t += nw) {
        const int n0 = t * 16;
        f32x4 acc[4] = {};
#pragma unroll
        for (int kc = 0; kc < 2; ++kc) {
            short8 aA = *(const short8*)&aggb[(size_t)(n0 + r) * DD + kc * 32 + g * 8];
            short8 aH = *(const short8*)&hb  [(size_t)(n0 + r) * DD + kc * 32 + g * 8];
#pragma unroll
            for (int ct = 0; ct < 4; ++ct) {
                acc[ct] = __builtin_amdgcn_mfma_f32_16x16x32_bf16(aA, bw[0][ct][kc], acc[ct], 0, 0, 0);
                acc[ct] = __builtin_amdgcn_mfma_f32_16x16x32_bf16(aH, bw[1][ct][kc], acc[ct], 0, 0, 0);
            }
        }
        // D: node = n0 + g*4 + e, outcol = ct*16 + r
#pragma unroll
        for (int ct = 0; ct < 4; ++ct)
#pragma unroll
            for (int e = 0; e < 4; ++e) {
                float v = acc[ct][e] + bias[ct];
                if (relu) v = fmaxf(v, 0.f);
                houtb[(size_t)(n0 + g * 4 + e) * DD + ct * 16 + r] = f2bf(v);
            }
    }
}

// ---------------- graph readout ----------------
__global__ void k_reduce(const u16* __restrict__ h, const int* __restrict__ batch,
                         float* __restrict__ out) {
    const int lane = threadIdx.x & 63;
    const int wid  = threadIdx.x >> 6;
    const int gw   = blockIdx.x * 4 + wid;
    const int start = gw * 64;
    if (start >= NN) return;
    const int endn = (start + 64 < NN) ? start + 64 : NN;
    float acc = 0.f;
    int gcur = batch[start];
    for (int i = start; i < endn; ++i) {
        int g = batch[i];
        if (g != gcur) {
            atomicAdd(&out[gcur * DD + lane], acc);
            acc = 0.f;
            gcur = g;
        }
        acc += bf2f(h[(size_t)i * DD + lane]);
    }
    atomicAdd(&out[gcur * DD + lane], acc);
}

extern "C" void kernel_launch(void* const* d_in, const int* in_sizes, int n_in,
                              void* d_out, int out_size, void* d_ws, size_t ws_size,
                              hipStream_t stream) {
    const float* x     = (const float*)d_in[0];
    const int*   ei    = (const int*)d_in[1];
    const int*   batch = (const int*)d_in[2];
    const float* Wl[3] = {(const float*)d_in[3], (const float*)d_in[6], (const float*)d_in[9]};
    const float* bl[3] = {(const float*)d_in[4], (const float*)d_in[7], (const float*)d_in[10]};
    const float* Wr[3] = {(const float*)d_in[5], (const float*)d_in[8], (const float*)d_in[11]};
    float* out = (float*)d_out;

    char* ws = (char*)d_ws;
    size_t off = 0;
    auto alloc = [&](size_t bytes) -> void* {
        void* p = ws + off;
        off = (off + bytes + 255) & ~(size_t)255;
        return p;
    };
    int*   counts  = (int*)  alloc((size_t)NN * 4);
    float* deg_inv = (float*)alloc((size_t)NN * 4);
    int*   row_off = (int*)  alloc(((size_t)NN + 1) * 4);
    int*   cursor  = (int*)  alloc((size_t)NN * 4);
    int*   bsum    = (int*)  alloc(128 * 4);
    int*   srcs    = (int*)  alloc((size_t)NE * 4);
    u16*   xb      = (u16*)  alloc((size_t)NN * DD * 2);
    u16*   aggb    = (u16*)  alloc((size_t)NN * DD * 2);
    u16*   hAb     = (u16*)  alloc((size_t)NN * DD * 2);
    u16*   hBb     = (u16*)  alloc((size_t)NN * DD * 2);

    const int* e_src = ei;       // edge_index[0]
    const int* e_dst = ei + NE;  // edge_index[1]

    hipMemsetAsync(counts, 0, (size_t)NN * 4, stream);
    hipMemsetAsync(out, 0, (size_t)NG * DD * 4, stream);

    k_count<<<2048, 256, 0, stream>>>(e_dst, counts);
    k_scan1<<<SCAN_NB, SCAN_B, 0, stream>>>(counts, row_off, deg_inv, bsum);
    k_scan2<<<1, 128, 0, stream>>>(bsum);
    k_scan3<<<(NN + 255) / 256, 256, 0, stream>>>(row_off, cursor, bsum);
    k_scatter<<<2048, 256, 0, stream>>>(e_src, e_dst, cursor, srcs);
    k_cvt<<<2048, 256, 0, stream>>>(x, xb);

    k_gather<<<2048, 256, 0, stream>>>(xb,  aggb, row_off, srcs, deg_inv);
    k_linear<<<512, 256, 0, stream>>>(aggb, xb,  hAb, Wl[0], bl[0], Wr[0], 1);
    k_gather<<<2048, 256, 0, stream>>>(hAb, aggb, row_off, srcs, deg_inv);
    k_linear<<<512, 256, 0, stream>>>(aggb, hAb, hBb, Wl[1], bl[1], Wr[1], 1);
    k_gather<<<2048, 256, 0, stream>>>(hBb, aggb, row_off, srcs, deg_inv);
    k_linear<<<512, 256, 0, stream>>>(aggb, hBb, hAb, Wl[2], bl[2], Wr[2], 0);

    k_reduce<<<(NN / 64 + 4) / 4, 256, 0, stream>>>(hAb, batch, out);
}

// Round 3
// 391.132 us; speedup vs baseline: 2.1281x; 1.0242x over previous
//
#include <hip/hip_runtime.h>
#include <cstdint>
#include <cstddef>

#define NN 100000
#define NE 1600000
#define DD 64
#define NG 64

#define EPB 4096
#define NBLK ((NE + EPB - 1) / EPB)      // 391
#define NBUCK ((NN + 511) / 512)         // 196
#define SCAN_N (NBUCK * NBLK)            // 76636
#define SCAN_CH ((SCAN_N + 1023) / 1024) // 75
#define BCAP 10240

typedef unsigned short u16;
typedef unsigned int u32;
typedef unsigned char u8;
typedef short short8 __attribute__((ext_vector_type(8)));
typedef float f32x4 __attribute__((ext_vector_type(4)));

__device__ __forceinline__ float bf2f(u16 h) {
    u32 u = ((u32)h) << 16;
    return __builtin_bit_cast(float, u);
}
__device__ __forceinline__ u16 f2bf(float f) {
    u32 u = __builtin_bit_cast(u32, f);
    u += 0x7fffu + ((u >> 16) & 1u);
    return (u16)(u >> 16);
}

// ---------------- CSR build: bucket partition, all-coalesced writes --------
// hist[b*NBLK + blk] = #edges of partition-block blk landing in bucket b.
__global__ void __launch_bounds__(256) k_hist(const int* __restrict__ dst,
                                              int* __restrict__ hist) {
    __shared__ int h[NBUCK];
    for (int i = threadIdx.x; i < NBUCK; i += 256) h[i] = 0;
    __syncthreads();
    const int base = blockIdx.x * EPB;
    const int end = (base + EPB < NE) ? base + EPB : NE;
    for (int i = base + threadIdx.x; i < end; i += 256)
        atomicAdd(&h[dst[i] >> 9], 1);
    __syncthreads();
    for (int i = threadIdx.x; i < NBUCK; i += 256)
        hist[i * NBLK + blockIdx.x] = h[i];
}

// Exclusive scan over hist[0..SCAN_N) in place (bucket-major order).
__global__ void __launch_bounds__(1024) k_scan(int* __restrict__ hist) {
    __shared__ int s[2][1024];
    const int t = threadIdx.x;
    const int base = t * SCAN_CH;
    int sum = 0;
    for (int i = 0; i < SCAN_CH; ++i) {
        int idx = base + i;
        if (idx < SCAN_N) sum += hist[idx];
    }
    s[0][t] = sum;
    __syncthreads();
    int sel = 0;
    for (int off = 1; off < 1024; off <<= 1) {
        int x = s[sel][t];
        if (t >= off) x += s[sel][t - off];
        s[sel ^ 1][t] = x;
        __syncthreads();
        sel ^= 1;
    }
    int run = s[sel][t] - sum; // exclusive prefix of this thread's chunk
    for (int i = 0; i < SCAN_CH; ++i) {
        int idx = base + i;
        if (idx < SCAN_N) {
            int v = hist[idx];
            hist[idx] = run;
            run += v;
        }
    }
}

// Partition edges into bucket-grouped u32 packs (dst_local<<17 | src).
__global__ void __launch_bounds__(256) k_part(const int* __restrict__ src,
                                              const int* __restrict__ dst,
                                              const int* __restrict__ excl,
                                              u32* __restrict__ part) {
    __shared__ int cnt[NBUCK];
    __shared__ int segb[NBUCK];
    __shared__ int diff[NBUCK];
    __shared__ int cur[NBUCK];
    __shared__ int sc[2][256];
    __shared__ u32 pk[EPB];
    __shared__ u8  bk[EPB];
    const int t = threadIdx.x;
    const int blk = blockIdx.x;
    const int base = blk * EPB;
    const int n = ((base + EPB < NE) ? EPB : NE - base);
    for (int i = t; i < NBUCK; i += 256) cnt[i] = 0;
    __syncthreads();

    int myb[EPB / 256];
    u32 mypk[EPB / 256];
#pragma unroll
    for (int j = 0; j < EPB / 256; ++j) {
        int i = t + j * 256;
        bool ok = i < n;
        int d = ok ? dst[base + i] : 0;
        int s2 = ok ? src[base + i] : 0;
        int b = d >> 9;
        myb[j] = b;
        mypk[j] = ((u32)(d & 511) << 17) | (u32)s2;
        if (ok) atomicAdd(&cnt[b], 1);
    }
    __syncthreads();
    // exclusive scan of cnt[0..NBUCK) with 256 threads
    int v = (t < NBUCK) ? cnt[t] : 0;
    sc[0][t] = v;
    __syncthreads();
    int sel = 0;
    for (int off = 1; off < 256; off <<= 1) {
        int x = sc[sel][t];
        if (t >= off) x += sc[sel][t - off];
        sc[sel ^ 1][t] = x;
        __syncthreads();
        sel ^= 1;
    }
    if (t < NBUCK) {
        int e = sc[sel][t] - v;
        segb[t] = e;
        cur[t] = e;
        diff[t] = excl[t * NBLK + blk] - e;
    }
    __syncthreads();
#pragma unroll
    for (int j = 0; j < EPB / 256; ++j) {
        int i = t + j * 256;
        if (i < n) {
            int pos = atomicAdd(&cur[myb[j]], 1);
            pk[pos] = mypk[j];
            bk[pos] = (u8)myb[j];
        }
    }
    __syncthreads();
    for (int p = t; p < n; p += 256)
        part[diff[bk[p]] + p] = pk[p];
}

// Per-bucket: per-dst counts -> row_off/deg_inv (coalesced), LDS scatter of
// srcs sorted by dst, coalesced flush.
__global__ void __launch_bounds__(512) k_bucket(const u32* __restrict__ part,
                                                const int* __restrict__ excl,
                                                int* __restrict__ row_off,
                                                int* __restrict__ srcs,
                                                float* __restrict__ deg_inv) {
    __shared__ int cnt[512];
    __shared__ int cur[512];
    __shared__ int sc[2][512];
    __shared__ int lsrc[BCAP];
    const int b = blockIdx.x;
    const int t = threadIdx.x;
    const int base = excl[b * NBLK];
    const int endp = (b == NBUCK - 1) ? NE : excl[(b + 1) * NBLK];
    const int n = endp - base;
    cnt[t] = 0;
    __syncthreads();
    for (int i = t; i < n; i += 512)
        atomicAdd(&cnt[part[base + i] >> 17], 1);
    __syncthreads();
    int v = cnt[t];
    sc[0][t] = v;
    __syncthreads();
    int sel = 0;
    for (int off = 1; off < 512; off <<= 1) {
        int x = sc[sel][t];
        if (t >= off) x += sc[sel][t - off];
        sc[sel ^ 1][t] = x;
        __syncthreads();
        sel ^= 1;
    }
    const int el = sc[sel][t] - v; // exclusive local offset
    const int g = b * 512 + t;
    if (g < NN) {
        row_off[g] = base + el;
        deg_inv[g] = (v > 0) ? 1.0f / (float)v : 0.0f;
    }
    if (b == NBUCK - 1 && t == 0) row_off[NN] = NE;
    cur[t] = el;
    __syncthreads();
    for (int i = t; i < n; i += 512) {
        u32 p = part[base + i];
        int pos = atomicAdd(&cur[p >> 17], 1);
        int s2 = (int)(p & 0x1FFFFu);
        if (pos < BCAP) lsrc[pos] = s2;
        else srcs[base + pos] = s2; // overflow fallback (never for this data)
    }
    __syncthreads();
    const int lim = (n < BCAP) ? n : BCAP;
    for (int i = t; i < lim; i += 512)
        srcs[base + i] = lsrc[i];
}

// ---------------- fp32 -> bf16 ----------------
__global__ void k_cvt(const float* __restrict__ x, u16* __restrict__ xb) {
    int i = blockIdx.x * blockDim.x + threadIdx.x;
    int stride = gridDim.x * blockDim.x;
    const int total = NN * DD / 4;
    for (; i < total; i += stride) {
        float4 v = ((const float4*)x)[i];
        u32 p0 = (u32)f2bf(v.x) | ((u32)f2bf(v.y) << 16);
        u32 p1 = (u32)f2bf(v.z) | ((u32)f2bf(v.w) << 16);
        uint2 pk; pk.x = p0; pk.y = p1;
        ((uint2*)xb)[i] = pk;
    }
}

// ---------------- gather: agg[n] = mean of h[src] rows (bf16 in/out) -------
__global__ void __launch_bounds__(256) k_gather(
    const u16* __restrict__ hin, u16* __restrict__ agg,
    const int* __restrict__ row_off, const int* __restrict__ srcs,
    const float* __restrict__ deg_inv) {
    __shared__ int ids[4][64];
    const int lane = threadIdx.x & 63;
    const int wid  = threadIdx.x >> 6;
    const int half = lane >> 5;
    const int fp   = (lane & 31) * 2;
    const int nw   = gridDim.x * 4;
    int n = blockIdx.x * 4 + wid;
    if (n >= NN) return;
    int beg = row_off[n], end = row_off[n + 1];
    int myid = (beg + lane < end) ? srcs[beg + lane] : 0;

#define PAIR(J, SLO, SHI) { \
        int _id = ids[wid][(J) + half]; \
        u32 _v = *(const u32*)&hin[(size_t)_id * DD + fp]; \
        SLO += __builtin_bit_cast(float, _v << 16); \
        SHI += __builtin_bit_cast(float, _v & 0xffff0000u); }

    while (true) {
        ids[wid][lane] = myid;
        __builtin_amdgcn_wave_barrier();
        int nn2 = n + nw;
        int beg2 = 0, end2 = 0;
        if (nn2 < NN) { beg2 = row_off[nn2]; end2 = row_off[nn2 + 1]; }
        myid = (nn2 < NN && beg2 + lane < end2) ? srcs[beg2 + lane] : 0;
        const float dinv = deg_inv[n];

        int deg = end - beg;
        int cnt = deg < 64 ? deg : 64;
        float s0 = 0.f, s1 = 0.f, t0 = 0.f, t1 = 0.f;
        float u0 = 0.f, u1 = 0.f, w0 = 0.f, w1 = 0.f;
        int jq = 0;
        for (; jq + 16 <= cnt; jq += 16) {
            PAIR(jq + 0,  s0, s1)
            PAIR(jq + 2,  t0, t1)
            PAIR(jq + 4,  u0, u1)
            PAIR(jq + 6,  w0, w1)
            PAIR(jq + 8,  s0, s1)
            PAIR(jq + 10, t0, t1)
            PAIR(jq + 12, u0, u1)
            PAIR(jq + 14, w0, w1)
        }
        for (; jq + 2 <= cnt; jq += 2) PAIR(jq, s0, s1)
        if (jq < cnt) {
            int _id = ids[wid][jq];
            if (half == 0) {
                u32 _v = *(const u32*)&hin[(size_t)_id * DD + fp];
                s0 += __builtin_bit_cast(float, _v << 16);
                s1 += __builtin_bit_cast(float, _v & 0xffff0000u);
            }
        }
        for (int base = 64; base < deg; base += 64) {
            __builtin_amdgcn_wave_barrier();
            int m = deg - base; if (m > 64) m = 64;
            if (lane < m) ids[wid][lane] = srcs[beg + base + lane];
            __builtin_amdgcn_wave_barrier();
            int j = 0;
            for (; j + 2 <= m; j += 2) PAIR(j, s0, s1)
            if (j < m) {
                int _id = ids[wid][j];
                if (half == 0) {
                    u32 _v = *(const u32*)&hin[(size_t)_id * DD + fp];
                    s0 += __builtin_bit_cast(float, _v << 16);
                    s1 += __builtin_bit_cast(float, _v & 0xffff0000u);
                }
            }
        }
        float aLo = (s0 + t0) + (u0 + w0);
        float aHi = (s1 + t1) + (u1 + w1);
        aLo += __shfl_xor(aLo, 32);
        aHi += __shfl_xor(aHi, 32);
        aLo *= dinv; aHi *= dinv;
        if (half == 0) {
            u32 pk = (u32)f2bf(aLo) | ((u32)f2bf(aHi) << 16);
            *(u32*)&agg[(size_t)n * DD + fp] = pk;
        }
        n = nn2;
        if (n >= NN) break;
        beg = beg2; end = end2;
        __builtin_amdgcn_wave_barrier();
    }
#undef PAIR
}

// ---------------- linear: hout = agg@Wl^T + bl + h@Wr^T (+relu), bf16 MFMA -
__global__ void __launch_bounds__(256) k_linear(
    const u16* __restrict__ aggb, const u16* __restrict__ hb,
    u16* __restrict__ houtb,
    const float* __restrict__ Wl, const float* __restrict__ bl,
    const float* __restrict__ Wr, int relu) {
    const int lane = threadIdx.x & 63;
    const int wid  = threadIdx.x >> 6;
    const int r = lane & 15, g = lane >> 4;
    const int nw = gridDim.x * 4;
    const int w0 = blockIdx.x * 4 + wid;

    short8 bw[2][4][2];
#pragma unroll
    for (int m = 0; m < 2; ++m) {
        const float* W = m ? Wr : Wl;
#pragma unroll
        for (int ct = 0; ct < 4; ++ct)
#pragma unroll
            for (int kc = 0; kc < 2; ++kc) {
                const float* p = W + (size_t)(ct * 16 + r) * DD + kc * 32 + g * 8;
                float4 q0 = *(const float4*)p;
                float4 q1 = *(const float4*)(p + 4);
                short8 t;
                t[0] = (short)f2bf(q0.x); t[1] = (short)f2bf(q0.y);
                t[2] = (short)f2bf(q0.z); t[3] = (short)f2bf(q0.w);
                t[4] = (short)f2bf(q1.x); t[5] = (short)f2bf(q1.y);
                t[6] = (short)f2bf(q1.z); t[7] = (short)f2bf(q1.w);
                bw[m][ct][kc] = t;
            }
    }
    float bias[4];
#pragma unroll
    for (int ct = 0; ct < 4; ++ct) bias[ct] = bl[ct * 16 + r];

    for (int t = w0; t < NN / 16; t += nw) {
        const int n0 = t * 16;
        f32x4 acc[4] = {};
#pragma unroll
        for (int kc = 0; kc < 2; ++kc) {
            short8 aA = *(const short8*)&aggb[(size_t)(n0 + r) * DD + kc * 32 + g * 8];
            short8 aH = *(const short8*)&hb  [(size_t)(n0 + r) * DD + kc * 32 + g * 8];
#pragma unroll
            for (int ct = 0; ct < 4; ++ct) {
                acc[ct] = __builtin_amdgcn_mfma_f32_16x16x32_bf16(aA, bw[0][ct][kc], acc[ct], 0, 0, 0);
                acc[ct] = __builtin_amdgcn_mfma_f32_16x16x32_bf16(aH, bw[1][ct][kc], acc[ct], 0, 0, 0);
            }
        }
#pragma unroll
        for (int ct = 0; ct < 4; ++ct)
#pragma unroll
            for (int e = 0; e < 4; ++e) {
                float v = acc[ct][e] + bias[ct];
                if (relu) v = fmaxf(v, 0.f);
                houtb[(size_t)(n0 + g * 4 + e) * DD + ct * 16 + r] = f2bf(v);
            }
    }
}

// ---------------- graph readout ----------------
__global__ void k_reduce(const u16* __restrict__ h, const int* __restrict__ batch,
                         float* __restrict__ out) {
    const int lane = threadIdx.x & 63;
    const int wid  = threadIdx.x >> 6;
    const int gw   = blockIdx.x * 4 + wid;
    const int start = gw * 64;
    if (start >= NN) return;
    const int endn = (start + 64 < NN) ? start + 64 : NN;
    float acc = 0.f;
    int gcur = batch[start];
    for (int i = start; i < endn; ++i) {
        int g = batch[i];
        if (g != gcur) {
            atomicAdd(&out[gcur * DD + lane], acc);
            acc = 0.f;
            gcur = g;
        }
        acc += bf2f(h[(size_t)i * DD + lane]);
    }
    atomicAdd(&out[gcur * DD + lane], acc);
}

extern "C" void kernel_launch(void* const* d_in, const int* in_sizes, int n_in,
                              void* d_out, int out_size, void* d_ws, size_t ws_size,
                              hipStream_t stream) {
    const float* x     = (const float*)d_in[0];
    const int*   ei    = (const int*)d_in[1];
    const int*   batch = (const int*)d_in[2];
    const float* Wl[3] = {(const float*)d_in[3], (const float*)d_in[6], (const float*)d_in[9]};
    const float* bl[3] = {(const float*)d_in[4], (const float*)d_in[7], (const float*)d_in[10]};
    const float* Wr[3] = {(const float*)d_in[5], (const float*)d_in[8], (const float*)d_in[11]};
    float* out = (float*)d_out;

    char* ws = (char*)d_ws;
    size_t off = 0;
    auto alloc = [&](size_t bytes) -> void* {
        void* p = ws + off;
        off = (off + bytes + 255) & ~(size_t)255;
        return p;
    };
    int*   hist    = (int*)  alloc((size_t)SCAN_N * 4);
    float* deg_inv = (float*)alloc((size_t)NN * 4);
    int*   row_off = (int*)  alloc(((size_t)NN + 1) * 4);
    int*   srcs    = (int*)  alloc((size_t)NE * 4);
    u16*   xb      = (u16*)  alloc((size_t)NN * DD * 2);
    u16*   aggb    = (u16*)  alloc((size_t)NN * DD * 2);
    u16*   hAb     = (u16*)  alloc((size_t)NN * DD * 2);
    u16*   hBb     = (u16*)  alloc((size_t)NN * DD * 2);
    // part aliases aggb: fully consumed by k_bucket before first k_gather
    // writes aggb (stream-ordered).
    u32*   part    = (u32*)aggb;

    const int* e_src = ei;       // edge_index[0]
    const int* e_dst = ei + NE;  // edge_index[1]

    hipMemsetAsync(out, 0, (size_t)NG * DD * 4, stream);

    k_hist<<<NBLK, 256, 0, stream>>>(e_dst, hist);
    k_scan<<<1, 1024, 0, stream>>>(hist);
    k_part<<<NBLK, 256, 0, stream>>>(e_src, e_dst, hist, part);
    k_bucket<<<NBUCK, 512, 0, stream>>>(part, hist, row_off, srcs, deg_inv);
    k_cvt<<<2048, 256, 0, stream>>>(x, xb);

    k_gather<<<2048, 256, 0, stream>>>(xb,  aggb, row_off, srcs, deg_inv);
    k_linear<<<512, 256, 0, stream>>>(aggb, xb,  hAb, Wl[0], bl[0], Wr[0], 1);
    k_gather<<<2048, 256, 0, stream>>>(hAb, aggb, row_off, srcs, deg_inv);
    k_linear<<<512, 256, 0, stream>>>(aggb, hAb, hBb, Wl[1], bl[1], Wr[1], 1);
    k_gather<<<2048, 256, 0, stream>>>(hBb, aggb, row_off, srcs, deg_inv);
    k_linear<<<512, 256, 0, stream>>>(aggb, hBb, hAb, Wl[2], bl[2], Wr[2], 0);

    k_reduce<<<(NN / 64 + 4) / 4, 256, 0, stream>>>(hAb, batch, out);
}

// Round 4
// 243.680 us; speedup vs baseline: 3.4159x; 1.6051x over previous
//
#include <hip/hip_runtime.h>
#include <cstdint>
#include <cstddef>

#define NN 100000
#define NE 1600000
#define DD 64
#define NG 64

#define EPB 4096
#define NBLK ((NE + EPB - 1) / EPB)      // 391
#define NBUCK ((NN + 511) / 512)         // 196
#define BCAP 10240

typedef unsigned short u16;
typedef unsigned int u32;
typedef unsigned char u8;
typedef short short8 __attribute__((ext_vector_type(8)));
typedef float f32x4 __attribute__((ext_vector_type(4)));

__device__ __forceinline__ float bf2f(u16 h) {
    u32 u = ((u32)h) << 16;
    return __builtin_bit_cast(float, u);
}
__device__ __forceinline__ u16 f2bf(float f) {
    u32 u = __builtin_bit_cast(u32, f);
    u += 0x7fffu + ((u >> 16) & 1u);
    return (u16)(u >> 16);
}

// ---------------- CSR build: bucket partition, all-coalesced writes --------
// hist[b*NBLK + blk] = #edges of partition-block blk landing in bucket b.
__global__ void __launch_bounds__(256) k_hist(const int* __restrict__ dst,
                                              int* __restrict__ hist) {
    __shared__ int h[NBUCK];
    for (int i = threadIdx.x; i < NBUCK; i += 256) h[i] = 0;
    __syncthreads();
    const int base = blockIdx.x * EPB;
    const int end = (base + EPB < NE) ? base + EPB : NE;
    for (int i = base + threadIdx.x; i < end; i += 256)
        atomicAdd(&h[dst[i] >> 9], 1);
    __syncthreads();
    for (int i = threadIdx.x; i < NBUCK; i += 256)
        hist[i * NBLK + blockIdx.x] = h[i];
}

// Per-bucket row scan: exclusive scan of hist[b*NBLK .. b*NBLK+NBLK) in place;
// bucket total -> btot[b].
__global__ void __launch_bounds__(512) k_rowscan(int* __restrict__ hist,
                                                 int* __restrict__ btot) {
    __shared__ int s[2][512];
    const int b = blockIdx.x;
    const int t = threadIdx.x;
    int v = (t < NBLK) ? hist[b * NBLK + t] : 0;
    s[0][t] = v;
    __syncthreads();
    int sel = 0;
    for (int off = 1; off < 512; off <<= 1) {
        int x = s[sel][t];
        if (t >= off) x += s[sel][t - off];
        s[sel ^ 1][t] = x;
        __syncthreads();
        sel ^= 1;
    }
    if (t < NBLK) hist[b * NBLK + t] = s[sel][t] - v;
    if (t == 511) btot[b] = s[sel][511];
}

// Scan bucket totals -> bucket bases; btot[NBUCK] = NE.
__global__ void __launch_bounds__(256) k_btscan(int* __restrict__ btot) {
    __shared__ int s[2][256];
    const int t = threadIdx.x;
    int v = (t < NBUCK) ? btot[t] : 0;
    s[0][t] = v;
    __syncthreads();
    int sel = 0;
    for (int off = 1; off < 256; off <<= 1) {
        int x = s[sel][t];
        if (t >= off) x += s[sel][t - off];
        s[sel ^ 1][t] = x;
        __syncthreads();
        sel ^= 1;
    }
    if (t < NBUCK) btot[t] = s[sel][t] - v;
    if (t == 0) btot[NBUCK] = NE;
}

// Partition edges into bucket-grouped u32 packs (dst_local<<17 | src).
__global__ void __launch_bounds__(256) k_part(const int* __restrict__ src,
                                              const int* __restrict__ dst,
                                              const int* __restrict__ excl,
                                              const int* __restrict__ btot,
                                              u32* __restrict__ part) {
    __shared__ int cnt[NBUCK];
    __shared__ int diff[NBUCK];
    __shared__ int cur[NBUCK];
    __shared__ int sc[2][256];
    __shared__ u32 pk[EPB];
    __shared__ u8  bk[EPB];
    const int t = threadIdx.x;
    const int blk = blockIdx.x;
    const int base = blk * EPB;
    const int n = ((base + EPB < NE) ? EPB : NE - base);
    for (int i = t; i < NBUCK; i += 256) cnt[i] = 0;
    __syncthreads();

    int myb[EPB / 256];
    u32 mypk[EPB / 256];
#pragma unroll
    for (int j = 0; j < EPB / 256; ++j) {
        int i = t + j * 256;
        bool ok = i < n;
        int d = ok ? dst[base + i] : 0;
        int s2 = ok ? src[base + i] : 0;
        int b = d >> 9;
        myb[j] = b;
        mypk[j] = ((u32)(d & 511) << 17) | (u32)s2;
        if (ok) atomicAdd(&cnt[b], 1);
    }
    __syncthreads();
    int v = (t < NBUCK) ? cnt[t] : 0;
    sc[0][t] = v;
    __syncthreads();
    int sel = 0;
    for (int off = 1; off < 256; off <<= 1) {
        int x = sc[sel][t];
        if (t >= off) x += sc[sel][t - off];
        sc[sel ^ 1][t] = x;
        __syncthreads();
        sel ^= 1;
    }
    if (t < NBUCK) {
        int e = sc[sel][t] - v;
        cur[t] = e;
        diff[t] = excl[t * NBLK + blk] + btot[t] - e;
    }
    __syncthreads();
#pragma unroll
    for (int j = 0; j < EPB / 256; ++j) {
        int i = t + j * 256;
        if (i < n) {
            int pos = atomicAdd(&cur[myb[j]], 1);
            pk[pos] = mypk[j];
            bk[pos] = (u8)myb[j];
        }
    }
    __syncthreads();
    for (int p = t; p < n; p += 256)
        part[diff[bk[p]] + p] = pk[p];
}

// Per-bucket: per-dst counts -> row_off/deg_inv (coalesced), LDS scatter of
// srcs sorted by dst, coalesced flush.
__global__ void __launch_bounds__(512) k_bucket(const u32* __restrict__ part,
                                                const int* __restrict__ btot,
                                                int* __restrict__ row_off,
                                                int* __restrict__ srcs,
                                                float* __restrict__ deg_inv) {
    __shared__ int cnt[512];
    __shared__ int cur[512];
    __shared__ int sc[2][512];
    __shared__ int lsrc[BCAP];
    const int b = blockIdx.x;
    const int t = threadIdx.x;
    const int base = btot[b];
    const int endp = btot[b + 1];
    const int n = endp - base;
    cnt[t] = 0;
    __syncthreads();
    for (int i = t; i < n; i += 512)
        atomicAdd(&cnt[part[base + i] >> 17], 1);
    __syncthreads();
    int v = cnt[t];
    sc[0][t] = v;
    __syncthreads();
    int sel = 0;
    for (int off = 1; off < 512; off <<= 1) {
        int x = sc[sel][t];
        if (t >= off) x += sc[sel][t - off];
        sc[sel ^ 1][t] = x;
        __syncthreads();
        sel ^= 1;
    }
    const int el = sc[sel][t] - v; // exclusive local offset
    const int g = b * 512 + t;
    if (g < NN) {
        row_off[g] = base + el;
        deg_inv[g] = (v > 0) ? 1.0f / (float)v : 0.0f;
    }
    if (b == NBUCK - 1 && t == 0) row_off[NN] = NE;
    cur[t] = el;
    __syncthreads();
    for (int i = t; i < n; i += 512) {
        u32 p = part[base + i];
        int pos = atomicAdd(&cur[p >> 17], 1);
        int s2 = (int)(p & 0x1FFFFu);
        if (pos < BCAP) lsrc[pos] = s2;
        else srcs[base + pos] = s2; // overflow fallback (never for this data)
    }
    __syncthreads();
    const int lim = (n < BCAP) ? n : BCAP;
    for (int i = t; i < lim; i += 512)
        srcs[base + i] = lsrc[i];
}

// ---------------- fp32 -> bf16 ----------------
__global__ void k_cvt(const float* __restrict__ x, u16* __restrict__ xb) {
    int i = blockIdx.x * blockDim.x + threadIdx.x;
    int stride = gridDim.x * blockDim.x;
    const int total = NN * DD / 4;
    for (; i < total; i += stride) {
        float4 v = ((const float4*)x)[i];
        u32 p0 = (u32)f2bf(v.x) | ((u32)f2bf(v.y) << 16);
        u32 p1 = (u32)f2bf(v.z) | ((u32)f2bf(v.w) << 16);
        uint2 pk; pk.x = p0; pk.y = p1;
        ((uint2*)xb)[i] = pk;
    }
}

// ---------------- gather: agg[n] = mean of h[src] rows (bf16 in/out) -------
__global__ void __launch_bounds__(256) k_gather(
    const u16* __restrict__ hin, u16* __restrict__ agg,
    const int* __restrict__ row_off, const int* __restrict__ srcs,
    const float* __restrict__ deg_inv) {
    __shared__ int ids[4][64];
    const int lane = threadIdx.x & 63;
    const int wid  = threadIdx.x >> 6;
    const int half = lane >> 5;
    const int fp   = (lane & 31) * 2;
    const int nw   = gridDim.x * 4;
    int n = blockIdx.x * 4 + wid;
    if (n >= NN) return;
    int beg = row_off[n], end = row_off[n + 1];
    int myid = (beg + lane < end) ? srcs[beg + lane] : 0;

#define PAIR(J, SLO, SHI) { \
        int _id = ids[wid][(J) + half]; \
        u32 _v = *(const u32*)&hin[(size_t)_id * DD + fp]; \
        SLO += __builtin_bit_cast(float, _v << 16); \
        SHI += __builtin_bit_cast(float, _v & 0xffff0000u); }

    while (true) {
        ids[wid][lane] = myid;
        __builtin_amdgcn_wave_barrier();
        int nn2 = n + nw;
        int beg2 = 0, end2 = 0;
        if (nn2 < NN) { beg2 = row_off[nn2]; end2 = row_off[nn2 + 1]; }
        myid = (nn2 < NN && beg2 + lane < end2) ? srcs[beg2 + lane] : 0;
        const float dinv = deg_inv[n];

        int deg = end - beg;
        int cnt = deg < 64 ? deg : 64;
        float s0 = 0.f, s1 = 0.f, t0 = 0.f, t1 = 0.f;
        float u0 = 0.f, u1 = 0.f, w0 = 0.f, w1 = 0.f;
        int jq = 0;
        for (; jq + 16 <= cnt; jq += 16) {
            PAIR(jq + 0,  s0, s1)
            PAIR(jq + 2,  t0, t1)
            PAIR(jq + 4,  u0, u1)
            PAIR(jq + 6,  w0, w1)
            PAIR(jq + 8,  s0, s1)
            PAIR(jq + 10, t0, t1)
            PAIR(jq + 12, u0, u1)
            PAIR(jq + 14, w0, w1)
        }
        for (; jq + 2 <= cnt; jq += 2) PAIR(jq, s0, s1)
        if (jq < cnt) {
            int _id = ids[wid][jq];
            if (half == 0) {
                u32 _v = *(const u32*)&hin[(size_t)_id * DD + fp];
                s0 += __builtin_bit_cast(float, _v << 16);
                s1 += __builtin_bit_cast(float, _v & 0xffff0000u);
            }
        }
        for (int base = 64; base < deg; base += 64) {
            __builtin_amdgcn_wave_barrier();
            int m = deg - base; if (m > 64) m = 64;
            if (lane < m) ids[wid][lane] = srcs[beg + base + lane];
            __builtin_amdgcn_wave_barrier();
            int j = 0;
            for (; j + 2 <= m; j += 2) PAIR(j, s0, s1)
            if (j < m) {
                int _id = ids[wid][j];
                if (half == 0) {
                    u32 _v = *(const u32*)&hin[(size_t)_id * DD + fp];
                    s0 += __builtin_bit_cast(float, _v << 16);
                    s1 += __builtin_bit_cast(float, _v & 0xffff0000u);
                }
            }
        }
        float aLo = (s0 + t0) + (u0 + w0);
        float aHi = (s1 + t1) + (u1 + w1);
        aLo += __shfl_xor(aLo, 32);
        aHi += __shfl_xor(aHi, 32);
        aLo *= dinv; aHi *= dinv;
        if (half == 0) {
            u32 pk = (u32)f2bf(aLo) | ((u32)f2bf(aHi) << 16);
            *(u32*)&agg[(size_t)n * DD + fp] = pk;
        }
        n = nn2;
        if (n >= NN) break;
        beg = beg2; end = end2;
        __builtin_amdgcn_wave_barrier();
    }
#undef PAIR
}

// ---------------- linear: hout = agg@Wl^T + bl + h@Wr^T (+relu), bf16 MFMA -
__global__ void __launch_bounds__(256) k_linear(
    const u16* __restrict__ aggb, const u16* __restrict__ hb,
    u16* __restrict__ houtb,
    const float* __restrict__ Wl, const float* __restrict__ bl,
    const float* __restrict__ Wr, int relu) {
    const int lane = threadIdx.x & 63;
    const int wid  = threadIdx.x >> 6;
    const int r = lane & 15, g = lane >> 4;
    const int nw = gridDim.x * 4;
    const int w0 = blockIdx.x * 4 + wid;

    short8 bw[2][4][2];
#pragma unroll
    for (int m = 0; m < 2; ++m) {
        const float* W = m ? Wr : Wl;
#pragma unroll
        for (int ct = 0; ct < 4; ++ct)
#pragma unroll
            for (int kc = 0; kc < 2; ++kc) {
                const float* p = W + (size_t)(ct * 16 + r) * DD + kc * 32 + g * 8;
                float4 q0 = *(const float4*)p;
                float4 q1 = *(const float4*)(p + 4);
                short8 t;
                t[0] = (short)f2bf(q0.x); t[1] = (short)f2bf(q0.y);
                t[2] = (short)f2bf(q0.z); t[3] = (short)f2bf(q0.w);
                t[4] = (short)f2bf(q1.x); t[5] = (short)f2bf(q1.y);
                t[6] = (short)f2bf(q1.z); t[7] = (short)f2bf(q1.w);
                bw[m][ct][kc] = t;
            }
    }
    float bias[4];
#pragma unroll
    for (int ct = 0; ct < 4; ++ct) bias[ct] = bl[ct * 16 + r];

    for (int t = w0; t < NN / 16; t += nw) {
        const int n0 = t * 16;
        f32x4 acc[4] = {};
#pragma unroll
        for (int kc = 0; kc < 2; ++kc) {
            short8 aA = *(const short8*)&aggb[(size_t)(n0 + r) * DD + kc * 32 + g * 8];
            short8 aH = *(const short8*)&hb  [(size_t)(n0 + r) * DD + kc * 32 + g * 8];
#pragma unroll
            for (int ct = 0; ct < 4; ++ct) {
                acc[ct] = __builtin_amdgcn_mfma_f32_16x16x32_bf16(aA, bw[0][ct][kc], acc[ct], 0, 0, 0);
                acc[ct] = __builtin_amdgcn_mfma_f32_16x16x32_bf16(aH, bw[1][ct][kc], acc[ct], 0, 0, 0);
            }
        }
#pragma unroll
        for (int ct = 0; ct < 4; ++ct)
#pragma unroll
            for (int e = 0; e < 4; ++e) {
                float v = acc[ct][e] + bias[ct];
                if (relu) v = fmaxf(v, 0.f);
                houtb[(size_t)(n0 + g * 4 + e) * DD + ct * 16 + r] = f2bf(v);
            }
    }
}

// ---------------- graph readout ----------------
__global__ void k_reduce(const u16* __restrict__ h, const int* __restrict__ batch,
                         float* __restrict__ out) {
    const int lane = threadIdx.x & 63;
    const int wid  = threadIdx.x >> 6;
    const int gw   = blockIdx.x * 4 + wid;
    const int start = gw * 64;
    if (start >= NN) return;
    const int endn = (start + 64 < NN) ? start + 64 : NN;
    float acc = 0.f;
    int gcur = batch[start];
    for (int i = start; i < endn; ++i) {
        int g = batch[i];
        if (g != gcur) {
            atomicAdd(&out[gcur * DD + lane], acc);
            acc = 0.f;
            gcur = g;
        }
        acc += bf2f(h[(size_t)i * DD + lane]);
    }
    atomicAdd(&out[gcur * DD + lane], acc);
}

extern "C" void kernel_launch(void* const* d_in, const int* in_sizes, int n_in,
                              void* d_out, int out_size, void* d_ws, size_t ws_size,
                              hipStream_t stream) {
    const float* x     = (const float*)d_in[0];
    const int*   ei    = (const int*)d_in[1];
    const int*   batch = (const int*)d_in[2];
    const float* Wl[3] = {(const float*)d_in[3], (const float*)d_in[6], (const float*)d_in[9]};
    const float* bl[3] = {(const float*)d_in[4], (const float*)d_in[7], (const float*)d_in[10]};
    const float* Wr[3] = {(const float*)d_in[5], (const float*)d_in[8], (const float*)d_in[11]};
    float* out = (float*)d_out;

    char* ws = (char*)d_ws;
    size_t off = 0;
    auto alloc = [&](size_t bytes) -> void* {
        void* p = ws + off;
        off = (off + bytes + 255) & ~(size_t)255;
        return p;
    };
    int*   hist    = (int*)  alloc((size_t)NBUCK * NBLK * 4);
    int*   btot    = (int*)  alloc(((size_t)NBUCK + 1) * 4);
    float* deg_inv = (float*)alloc((size_t)NN * 4);
    int*   row_off = (int*)  alloc(((size_t)NN + 1) * 4);
    int*   srcs    = (int*)  alloc((size_t)NE * 4);
    u16*   xb      = (u16*)  alloc((size_t)NN * DD * 2);
    u16*   aggb    = (u16*)  alloc((size_t)NN * DD * 2);
    u16*   hAb     = (u16*)  alloc((size_t)NN * DD * 2);
    u16*   hBb     = (u16*)  alloc((size_t)NN * DD * 2);
    // part aliases aggb: fully consumed by k_bucket before first k_gather
    // writes aggb (stream-ordered).
    u32*   part    = (u32*)aggb;

    const int* e_src = ei;       // edge_index[0]
    const int* e_dst = ei + NE;  // edge_index[1]

    hipMemsetAsync(out, 0, (size_t)NG * DD * 4, stream);

    k_hist<<<NBLK, 256, 0, stream>>>(e_dst, hist);
    k_rowscan<<<NBUCK, 512, 0, stream>>>(hist, btot);
    k_btscan<<<1, 256, 0, stream>>>(btot);
    k_part<<<NBLK, 256, 0, stream>>>(e_src, e_dst, hist, btot, part);
    k_bucket<<<NBUCK, 512, 0, stream>>>(part, btot, row_off, srcs, deg_inv);
    k_cvt<<<2048, 256, 0, stream>>>(x, xb);

    k_gather<<<2048, 256, 0, stream>>>(xb,  aggb, row_off, srcs, deg_inv);
    k_linear<<<512, 256, 0, stream>>>(aggb, xb,  hAb, Wl[0], bl[0], Wr[0], 1);
    k_gather<<<2048, 256, 0, stream>>>(hAb, aggb, row_off, srcs, deg_inv);
    k_linear<<<512, 256, 0, stream>>>(aggb, hAb, hBb, Wl[1], bl[1], Wr[1], 1);
    k_gather<<<2048, 256, 0, stream>>>(hBb, aggb, row_off, srcs, deg_inv);
    k_linear<<<512, 256, 0, stream>>>(aggb, hBb, hAb, Wl[2], bl[2], Wr[2], 0);

    k_reduce<<<(NN / 64 + 4) / 4, 256, 0, stream>>>(hAb, batch, out);
}